// Round 3
// baseline (282.484 us; speedup 1.0000x reference)
//
#include <hip/hip_runtime.h>
#include <math.h>

typedef _Float16 f16x8 __attribute__((ext_vector_type(8)));
typedef float    f32x4 __attribute__((ext_vector_type(4)));

constexpr int kT    = 512;   // sequence length
constexpr int kH    = 16;    // hidden
constexpr int kL    = 8;     // layers
constexpr int kG    = 64;    // gates
constexpr int kNB   = 8;     // batch per block
constexpr int kPad  = 24;    // f16 row stride (48 B)
constexpr int kRows = 9;     // 8 batch rows + permanent zero row
constexpr int kSlots= 16;    // ring depth
constexpr int kLyr  = kL + 1;               // lyr 0 = x, lyr 1+l = layer l h
constexpr int kSE   = kLyr * kRows * kPad;  // f16 elems per slot (1944)
constexpr int kIters= 33;    // 528 wall steps >= last useful wall 525

constexpr float kL2E = 1.4426950408889634f;

__device__ __forceinline__ float ex2(float w)  { return __builtin_amdgcn_exp2f(w); }
__device__ __forceinline__ float rcpf(float e) { return __builtin_amdgcn_rcpf(e); }

// Round-11: 7-transcendental cell update (was 10).
//  - c_new = [c*Di*Dg + (1-Eg)*Df] / (Df*Di*Dg)   -> 1 rcp (was 3)
//  - h     = (1-Ec) / (Do*(1+Ec))                 -> 1 rcp (was 2)
//  - 5 exps mandatory; exp2 args clamped (<=40 for i,f,g; <=60 for o,c)
//    so the triple-product denominator stays < 2^120 (no inf/NaN paths;
//    clamps change sigmoids by <1e-12 only in full saturation)
//  - rest identical to round-10: 16 waves (layer x tile), barrier lockstep
//    skew-2 ring, lgkmcnt-only drain, b128 B1/B2 reads, b16 h publish
__global__ __launch_bounds__(1024, 4)
void lstm_w16(const float* __restrict__ x,
              const float* __restrict__ Wih, const float* __restrict__ Whh,
              const float* __restrict__ bih, const float* __restrict__ bhh,
              const float* __restrict__ Wp,  const float* __restrict__ bpos,
              const float* __restrict__ Wo,  const float* __restrict__ bori,
              float* __restrict__ out)
{
    const int tid  = threadIdx.x;
    const int wv   = tid >> 6;
    const int l    = wv >> 1;
    const int T    = wv & 1;
    const int lane = tid & 63;
    const int n    = lane & 15;
    const int q    = lane >> 4;
    const int bn   = n & 7;
    const bool bact = ((q >> 1) == (n >> 3));

    __shared__ __align__(16) _Float16 hb[kSlots][kLyr][kRows][kPad];  // 62208 B

    {   // zero-init LDS
        int* hz = (int*)&hb[0][0][0][0];
        for (int i = tid; i < (int)(sizeof(hb) / 4); i += 1024) hz[i] = 0;
    }
    __syncthreads();

    // ---- A fragments, scaled; plain-layout column map u = (q&1)*8 + j ----
    // A row m=n: W row = (n&3)*16 + (n>>2) + 4*(q>>1) + 8T
    // scale: gate (n&3)==2 (g) -> -2*L2E else -L2E
    const float asc = ((n & 3) == 2) ? (-2.0f * kL2E) : (-kL2E);
    auto loadA = [&](const float* W) -> f16x8 {
        const int wrow = (n & 3) * 16 + (n >> 2) + 4 * (q >> 1) + 8 * T;
        const float* src = W + (size_t)l * kG * kH + wrow * kH;
        f16x8 a;
        #pragma unroll
        for (int j = 0; j < 8; ++j)
            a[j] = (_Float16)(asc * src[(q & 1) * 8 + j]);
        return a;
    };
    const f16x8 A1 = loadA(Wih);
    const f16x8 A2 = loadA(Whh);

    // ---- scaled bias as MFMA C-init: reg r = gate r, unit q+4*(n>>3)+8T ----
    const int u0 = q + 4 * (n >> 3) + 8 * T;    // this lane's single unit
    f32x4 bias;
    #pragma unroll
    for (int r = 0; r < 4; ++r) {
        const float sc = (r == 2) ? (-2.0f * kL2E) : (-kL2E);
        const int g0 = l * kG + r * 16 + u0;
        bias[r] = sc * (bih[g0] + bhh[g0]);
    }

    // ---- LDS pointers (plain layout) ----
    const int boff = (bact ? bn * kPad : 8 * kPad) + (q & 1) * 8;
    const _Float16* b1b = &hb[0][l    ][0][0] + boff;   // v-input (x / h_{l-1})
    const _Float16* b2b = &hb[0][l + 1][0][0] + boff;   // own h
    _Float16* hw = &hb[0][l + 1][bn][u0];               // h publish (b16)

    // ---- x staging (layer-0 wave pair): lane covers batch lane>>3, unit xu
    //      slot k holds x(k+1); prime slots 15,0,1 with x(0..2);
    //      regs xa,xb,xc hold x(3),x(4),x(5) (2-wall load-to-use distance) ----
    const int xu = (lane & 7) + 8 * T;
    _Float16* xw = &hb[0][0][lane >> 3][xu];
    const float* xg_ptr =
        x + ((size_t)(blockIdx.x * kNB + (lane >> 3)) * kT) * kH;
    float xa = 0.f, xb = 0.f, xc = 0.f;
    if (l == 0) {
        #pragma unroll
        for (int t = 0; t < 3; ++t)
            *(xw + ((t + 15) & 15) * kSE) = (_Float16)xg_ptr[t * kH + xu];
        xa = xg_ptr[3 * kH + xu];
        xb = xg_ptr[4 * kH + xu];
        xc = xg_ptr[5 * kH + xu];
    }
    __syncthreads();

    // ---- prime: dIn(t=0) from slot 15 (x(0) for l=0, zeros for l>0) ----
    const f16x8 B1p = *(const f16x8*)(b1b + 15 * kSE);
    f32x4 dIn = __builtin_amdgcn_mfma_f32_16x16x32_f16(A1, B1p, bias, 0, 0, 0);

    float c0 = 0.f;               // plain (unscaled) cell state
    const int tl = 2 * l;

    #pragma unroll 1
    for (int it = 0; it < kIters; ++it) {
        const int sb = it * 16;
        #pragma unroll
        for (int k = 0; k < 16; ++k) {
            const int s = sb + k;
            const int slotR = k * kSE;
            const int slotW = ((k + 1) & 15) * kSE;
            const int slotX = ((k + 2) & 15) * kSE;
            const bool active = ((unsigned)(s - tl) < (unsigned)kT);

            // B2 = own h(t-1), written wall s-1 -> slot s&15 (barrier-fenced)
            const f16x8 B2r = *(const f16x8*)(b2b + slotR);
            // B1(next) early: upstream h / x, consumed by dIn MFMA at body end
            const f16x8 B1n = *(const f16x8*)(b1b + slotR);

            // recurrent half: d = A2*h(t-1) + dIn(t)  [chain head]
            // d0 = -L2E*i, d1 = -L2E*f, d2 = -2L2E*g, d3 = -L2E*o
            f32x4 d = __builtin_amdgcn_mfma_f32_16x16x32_f16(A2, B2r, dIn, 0, 0, 0);

            // ---- 7-trans cell update (merged denominators) ----
            const float Ei = ex2(fminf(d[0], 40.0f));   // e^-i
            const float Ef = ex2(fminf(d[1], 40.0f));   // e^-f
            const float Eg = ex2(fminf(d[2], 40.0f));   // e^-2g
            const float Eo = ex2(fminf(d[3], 60.0f));   // e^-o
            const float Dg = 1.0f + Eg;
            const float Df = 1.0f + Ef;
            const float P1  = fmaf(Ei, Dg, Dg);         // Di*Dg
            const float den = Df * P1;                  // Df*Di*Dg  (< 2^120)
            const float t2  = fmaf(-Eg, Df, Df);        // (1-Eg)*Df
            const float num = fmaf(c0, P1, t2);         // c*Di*Dg + (1-Eg)*Df
            float cn = num * rcpf(den);                 // c_new = sf*c + si*tanh(g)
            cn = active ? cn : 0.0f;
            c0 = cn;
            const float ac = fminf(cn * (-2.0f * kL2E), 60.0f);
            const float Ec = ex2(ac);                   // e^-2c
            const float Do = 1.0f + Eo;
            const float R2 = rcpf(fmaf(Do, Ec, Do));    // 1/(Do*(1+Ec))
            const float h0 = fmaf(-Ec, R2, R2);         // sig(o)*tanh(c)

            // publish h(t) -> slot s+1 (own recurrence + downstream + head)
            *(hw + slotW) = (_Float16)h0;

            if (l == 0) {                    // publish x(s+3), rotate prefetch
                *(xw + slotX) = (_Float16)xa;
                xa = xb; xb = xc;
                int tn = s + 6; if (tn > kT - 1) tn = kT - 1;
                xc = xg_ptr[(size_t)tn * kH + xu];
            }

            // input half for next wall step (off-chain), bias rides C
            dIn = __builtin_amdgcn_mfma_f32_16x16x32_f16(A1, B1n, bias, 0, 0, 0);

            // end of wall step: drain DS (h/x writes), barrier.
            // vmcnt intentionally NOT drained (x prefetch spans barriers).
            asm volatile("s_waitcnt lgkmcnt(0)\n\ts_barrier" ::: "memory");
        }
    }

    __syncthreads();

    // ---- head: layer-7 h(511) written at wall 525 -> slot (525+1)&15 = 14 ----
    if (wv == 15) {
        const int bb = lane >> 3;
        const int r  = lane & 7;
        if (r < 6) {
            const bool  isP   = (r < 3);
            const float* wrow = isP ? (Wp + r * kH) : (Wo + (r - 3) * kH);
            float acc = isP ? bpos[r] : bori[r - 3];
            #pragma unroll
            for (int u = 0; u < kH; ++u)
                acc = fmaf((float)hb[14][kL][bb][u], wrow[u], acc);
            if (!isP) {
                const float Et = ex2(-2.0f * kL2E * acc);
                acc = fmaf(2.0f, rcpf(1.0f + Et), -1.0f);
            }
            out[(size_t)(blockIdx.x * kNB + bb) * 6 + r] = acc;
        }
    }
}

extern "C" void kernel_launch(void* const* d_in, const int* in_sizes, int n_in,
                              void* d_out, int out_size, void* d_ws, size_t ws_size,
                              hipStream_t stream) {
    const float* x    = (const float*)d_in[0];
    const float* Wih  = (const float*)d_in[1];
    const float* Whh  = (const float*)d_in[2];
    const float* bih  = (const float*)d_in[3];
    const float* bhh  = (const float*)d_in[4];
    const float* Wp   = (const float*)d_in[5];
    const float* bpos = (const float*)d_in[6];
    const float* Wo   = (const float*)d_in[7];
    const float* bori = (const float*)d_in[8];
    float* out = (float*)d_out;

    const int B = in_sizes[0] / (kT * kH);   // 2048
    lstm_w16<<<dim3(B / kNB), dim3(1024), 0, stream>>>(x, Wih, Whh, bih, bhh,
                                                       Wp, bpos, Wo, bori, out);
}